// Round 6
// baseline (159.797 us; speedup 1.0000x reference)
//
#include <hip/hip_runtime.h>
#include <cmath>

// CNEncoder reduced form (MCMC/graph path cancels; see round-0 derivation):
//   P_i = sum_j nx[i,j]; S_i = sum_j rf[i,j]; scale_i = P_i/(S_i+EPS)
//   t = rf*scale; global tmin/tmax/mean -> affine out = rf*(scale_i*A)+B
//   reg_loss = sum(rf^2)*1e-4
// st = sum_i sc_i*S_i is computed as sum_i P_i (rel. err ~7e-12, EPS/S).
//
// L3 choreography (verified r5: k_stats FETCH=244MB ~= nx only):
//   nx read with NT loads (evict-first), rf normal loads (L3-resident),
//   out written with NT stores (doesn't evict rf).
//
// k_stats is ILP-restructured (r5 post-mortem: VGPR=24, 2 loads in flight,
// latency-bound at 9.8% VALUBusy): 4 rows per wave, interleaved -> 8
// independent loads in flight; all reduce chains emitted together;
// per-wave partials, no LDS/barrier.

static constexpr int NS = 20000;
static constexpr int NG = 3000;
static constexpr int G4 = NG / 4;        // 750 fv4/row, row stride 12000 B
static constexpr int RW = 4;             // rows per wave
static constexpr int NWAVE = NS / RW;    // 5000 waves
static constexpr int NB = NWAVE / 4;     // 1250 blocks of 4 waves
static constexpr float EPS = 1e-8f;

typedef float fv4 __attribute__((ext_vector_type(4)));

// ws floats: [0,NS) S | [NS,2NS) P | [2NS,2NS+NWAVE) PST | +NWAVE PSQ
//            | +2*NWAVE PMN | +3*NWAVE PMX | then AB[2]

// ---- pass 1: per-row stats, 4 rows interleaved per wave ----
__global__ __launch_bounds__(256) void k_stats(
    const fv4* __restrict__ nx, const fv4* __restrict__ rf,
    float* __restrict__ S, float* __restrict__ P,
    float* __restrict__ PST, float* __restrict__ PSQ,
    float* __restrict__ PMN, float* __restrict__ PMX)
{
    const int wid  = threadIdx.x >> 6;
    const int lane = threadIdx.x & 63;
    const int w    = blockIdx.x * 4 + wid;   // global wave id, 0..NWAVE-1
    const int row0 = w * RW;
    const fv4* r0 = rf + (size_t)row0 * G4;
    const fv4* n0 = nx + (size_t)row0 * G4;

    float s[RW], p[RW], mn[RW], mx[RW];
    float q = 0.f;
    #pragma unroll
    for (int k = 0; k < RW; ++k) {
        s[k] = 0.f; p[k] = 0.f; mn[k] = INFINITY; mx[k] = -INFINITY;
    }

    for (int c = lane; c < G4; c += 64) {
        fv4 a[RW], b[RW];
        #pragma unroll
        for (int k = 0; k < RW; ++k) a[k] = r0[(size_t)k * G4 + c];
        #pragma unroll
        for (int k = 0; k < RW; ++k) b[k] = __builtin_nontemporal_load(n0 + (size_t)k * G4 + c);
        #pragma unroll
        for (int k = 0; k < RW; ++k) {
            s[k] += (a[k].x + a[k].y) + (a[k].z + a[k].w);
            q    += a[k].x * a[k].x + a[k].y * a[k].y + a[k].z * a[k].z + a[k].w * a[k].w;
            mn[k] = fminf(mn[k], fminf(fminf(a[k].x, a[k].y), fminf(a[k].z, a[k].w)));
            mx[k] = fmaxf(mx[k], fmaxf(fmaxf(a[k].x, a[k].y), fmaxf(a[k].z, a[k].w)));
            p[k] += (b[k].x + b[k].y) + (b[k].z + b[k].w);
        }
    }

    // 17 independent 6-step shuffle chains, emitted together
    #pragma unroll
    for (int off = 32; off > 0; off >>= 1) {
        #pragma unroll
        for (int k = 0; k < RW; ++k) {
            s[k] += __shfl_down(s[k], off);
            p[k] += __shfl_down(p[k], off);
            mn[k] = fminf(mn[k], __shfl_down(mn[k], off));
            mx[k] = fmaxf(mx[k], __shfl_down(mx[k], off));
        }
        q += __shfl_down(q, off);
    }

    if (lane == 0) {
        float st = 0.f, tmn = INFINITY, tmx = -INFINITY;
        #pragma unroll
        for (int k = 0; k < RW; ++k) {
            S[row0 + k] = s[k];
            P[row0 + k] = p[k];
            const float sc = p[k] / (s[k] + EPS);
            st += p[k];
            tmn = fminf(tmn, mn[k] * sc);
            tmx = fmaxf(tmx, mx[k] * sc);
        }
        PST[w] = st; PSQ[w] = q; PMN[w] = tmn; PMX[w] = tmx;
    }
}

// ---- pass 2: fold NWAVE wave partials into {A,B} and reg_loss ----
__global__ __launch_bounds__(256) void k_scalars(
    const float* __restrict__ PST, const float* __restrict__ PSQ,
    const float* __restrict__ PMN, const float* __restrict__ PMX,
    float* __restrict__ AB, float* __restrict__ loss_out)
{
    double st = 0.0, sq = 0.0;
    float tmn = INFINITY, tmx = -INFINITY;
    for (int i = threadIdx.x; i < NWAVE; i += 256) {
        st += (double)PST[i];
        sq += (double)PSQ[i];
        tmn = fminf(tmn, PMN[i]);
        tmx = fmaxf(tmx, PMX[i]);
    }
    #pragma unroll
    for (int off = 32; off > 0; off >>= 1) {
        st += __shfl_down(st, off);
        sq += __shfl_down(sq, off);
        tmn = fminf(tmn, __shfl_down(tmn, off));
        tmx = fmaxf(tmx, __shfl_down(tmx, off));
    }
    __shared__ double lst[4], lsq[4];
    __shared__ float lmn[4], lmx[4];
    const int wid = threadIdx.x >> 6;
    if ((threadIdx.x & 63) == 0) { lst[wid] = st; lsq[wid] = sq; lmn[wid] = tmn; lmx[wid] = tmx; }
    __syncthreads();
    if (threadIdx.x == 0) {
        st  = (lst[0] + lst[1]) + (lst[2] + lst[3]);
        sq  = (lsq[0] + lsq[1]) + (lsq[2] + lsq[3]);
        tmn = fminf(fminf(lmn[0], lmn[1]), fminf(lmn[2], lmn[3]));
        tmx = fmaxf(fmaxf(lmx[0], lmx[1]), fmaxf(lmx[2], lmx[3]));
        const float rmin = tmn * 0.8f;
        const float rmax = tmx * 1.2f;
        const float a = (rmax - rmin) / (tmx - tmn + EPS);
        const float mean_t = (float)(st / (double)((long long)NS * (long long)NG));
        const float mean_u = (mean_t - tmn) * a + rmin;
        AB[0] = a / mean_u;
        AB[1] = (rmin - tmn * a) / mean_u;
        *loss_out = (float)(sq * 1e-4);
    }
}

// ---- pass 3: out = rf*c_row + B; wave per row; NT stores ----
__global__ __launch_bounds__(256) void k_finalize(
    const fv4* __restrict__ rf,
    const float* __restrict__ S, const float* __restrict__ P,
    const float* __restrict__ AB,
    fv4* __restrict__ out)
{
    const int row  = blockIdx.x * 4 + (threadIdx.x >> 6);
    const int lane = threadIdx.x & 63;
    const float A = AB[0], B = AB[1];
    const float c = (P[row] / (S[row] + EPS)) * A;
    const fv4* r = rf + (size_t)row * G4;
    fv4* o = out + (size_t)row * G4;
    for (int i = lane; i < G4; i += 64) {
        fv4 a = r[i];
        fv4 v;
        v.x = fmaf(a.x, c, B);
        v.y = fmaf(a.y, c, B);
        v.z = fmaf(a.z, c, B);
        v.w = fmaf(a.w, c, B);
        __builtin_nontemporal_store(v, o + i);
    }
}

extern "C" void kernel_launch(void* const* d_in, const int* in_sizes, int n_in,
                              void* d_out, int out_size, void* d_ws, size_t ws_size,
                              hipStream_t stream) {
    const float* nx = (const float*)d_in[0];   // norm_x
    const float* rf = (const float*)d_in[1];   // reconstructed_features
    // d_in[2] (edge_index) unused: effect on output < 1e-11 relative.
    float* out = (float*)d_out;
    float* ws  = (float*)d_ws;
    float* S   = ws;
    float* P   = ws + NS;
    float* PST = ws + 2 * NS;
    float* PSQ = PST + NWAVE;
    float* PMN = PST + 2 * NWAVE;
    float* PMX = PST + 3 * NWAVE;
    float* AB  = PST + 4 * NWAVE;
    float* loss_out = out + (out_size - 1);

    k_stats   <<<NB,     256, 0, stream>>>((const fv4*)nx, (const fv4*)rf,
                                           S, P, PST, PSQ, PMN, PMX);
    k_scalars <<<1,      256, 0, stream>>>(PST, PSQ, PMN, PMX, AB, loss_out);
    k_finalize<<<NS / 4, 256, 0, stream>>>((const fv4*)rf, S, P, AB, (fv4*)out);
}